// Round 4
// baseline (96.522 us; speedup 1.0000x reference)
//
#include <hip/hip_runtime.h>
#include <math.h>

#define BB 4
#define NN 16384
#define CC 128
#define MM 128
#define SS 512
#define OUT_ROW 131                    // 3 coords + 128 features
#define NSEG 256                       // 16384 / 64 segments per box
#define ELEMS_PER_BOX (SS * OUT_ROW)   // 67072
#define BLOCKS_PER_BOX (ELEMS_PER_BOX / 256)  // 262 (exact)

// ---------------- K1: per-box stable in-box index selection ----------------
// 512 blocks (one per box) x 512 threads (8 waves).
// Emits ws_idx[bm][0..SS) with the row%cnt wrap ALREADY applied, so the
// gather kernel is pure streaming with no runtime division.
__global__ __launch_bounds__(512) void k1_select(
    const float* __restrict__ points,   // (B, N, 3)
    const float* __restrict__ boxes,    // (B, M, 7)
    int* __restrict__ ws_idx,           // (B*M, SS)
    int* __restrict__ ws_cnt,           // (B*M)
    float* __restrict__ out_flag)       // (B*M) as float 0/1
{
    const int bm   = blockIdx.x;
    const int b    = bm >> 7;
    const int m    = bm & (MM - 1);
    const int tid  = threadIdx.x;
    const int lane = tid & 63;
    const int wave = tid >> 6;

    __shared__ unsigned long long s_mask[NSEG];
    __shared__ int s_wsum[4];

    // box params, enlarged: cz -= 0.5, d* += 1.0
    const float* bx = boxes + (size_t)(b * MM + m) * 7;
    const float cx  = bx[0];
    const float cy  = bx[1];
    const float cz  = __fadd_rn(bx[2], -0.5f);
    const float hx  = __fmul_rn(__fadd_rn(bx[3], 1.0f), 0.5f);
    const float hy  = __fmul_rn(__fadd_rn(bx[4], 1.0f), 0.5f);
    const float hz  = __fmul_rn(__fadd_rn(bx[5], 1.0f), 0.5f);
    const float yaw = bx[6];
    const float cosa = (float)cos((double)yaw);
    const float sina = (float)sin((double)yaw);
    const float zc   = __fadd_rn(cz, hz);

    const float* pbase = points + (size_t)b * NN * 3;

    // ---- Pass A: wave w handles segments [w*32, w*32+32) ----
    #pragma unroll 4
    for (int k = 0; k < 32; ++k) {
        const int s = wave * 32 + k;
        const int i = s * 64 + lane;
        const float px = pbase[i * 3 + 0];
        const float py = pbase[i * 3 + 1];
        const float pz = pbase[i * 3 + 2];
        const float sx = __fadd_rn(px, -cx);
        const float sy = __fadd_rn(py, -cy);
        const float lx = __fadd_rn(__fmul_rn(sx, cosa), __fmul_rn(sy, sina));
        const float ly = __fadd_rn(__fmul_rn(-sx, sina), __fmul_rn(sy, cosa));
        const bool in_box = (fabsf(lx) < hx) & (fabsf(ly) < hy) &
                            (fabsf(__fadd_rn(pz, -zc)) <= hz);
        const unsigned long long mask = __ballot(in_box);
        if (lane == 0) s_mask[s] = mask;
    }
    __syncthreads();

    // ---- Pass B: prefix scan over 256 segment counts (threads 0..255) ----
    unsigned long long mymask = 0ull;
    int c = 0;
    if (tid < NSEG) {
        mymask = s_mask[tid];
        c = __popcll(mymask);
    }
    int inc = c;
    #pragma unroll
    for (int d = 1; d < 64; d <<= 1) {
        int v = __shfl_up(inc, d);
        if (lane >= d) inc += v;
    }
    if (tid < NSEG && lane == 63) s_wsum[wave] = inc;
    __syncthreads();

    int woff = 0, total = 0;
    #pragma unroll
    for (int w = 0; w < 4; ++w) {
        const int v = s_wsum[w];
        if (w < wave) woff += v;
        total += v;
    }

    int* dst = ws_idx + (size_t)bm * SS;

    // ---- Pass C: emit indices (stable ascending order), first SS only ----
    if (tid < NSEG) {
        int base = woff + inc - c;          // exclusive prefix
        if (base < SS) {
            unsigned long long mk = mymask;
            while (mk) {
                const int bit = __ffsll(mk) - 1;
                mk &= mk - 1;
                dst[base] = tid * 64 + bit;
                if (++base >= SS) break;
            }
        }
    }
    __syncthreads();

    // ---- Pass D: expand with row % cnt wrap so K2 needs no division ----
    const int cnt = total;
    if (cnt > 0) {
        for (int row = cnt + tid; row < SS; row += 512)
            dst[row] = dst[row % cnt];
    }
    if (tid == 0) {
        ws_cnt[bm] = cnt;
        out_flag[bm] = (cnt == 0) ? 1.0f : 0.0f;
    }
}

// ---------------- K2: flat streaming gather ----------------
// One thread per output element. Dense, fully-coalesced NT stores;
// coalesced scalar loads from the L2/LLC-resident feature slice.
__global__ __launch_bounds__(256) void k2_gather(
    const float* __restrict__ points,
    const float* __restrict__ feats,    // (B, N, C)
    const int* __restrict__ ws_idx,
    const int* __restrict__ ws_cnt,
    float* __restrict__ out_feat)       // (B, M, S, 131)
{
    const int bid = blockIdx.x;
    const int bm  = bid / BLOCKS_PER_BOX;                  // box-uniform block
    const int rem = (bid - bm * BLOCKS_PER_BOX) * 256 + threadIdx.x;
    const int row = rem / OUT_ROW;
    const int col = rem - row * OUT_ROW;

    const int cnt = ws_cnt[bm];
    float v = 0.0f;
    if (cnt > 0) {
        const int pi = ws_idx[(size_t)bm * SS + row];
        const int b  = bm >> 7;
        v = (col < 3) ? points[((size_t)b * NN + pi) * 3 + col]
                      : feats[((size_t)b * NN + pi) * CC + (col - 3)];
    }
    __builtin_nontemporal_store(v, out_feat + (size_t)bm * ELEMS_PER_BOX + rem);
}

extern "C" void kernel_launch(void* const* d_in, const int* in_sizes, int n_in,
                              void* d_out, int out_size, void* d_ws, size_t ws_size,
                              hipStream_t stream) {
    const float* points = (const float*)d_in[0];
    const float* feats  = (const float*)d_in[1];
    const float* boxes  = (const float*)d_in[2];
    float* out_feat = (float*)d_out;
    float* out_flag = (float*)d_out + (size_t)BB * MM * SS * OUT_ROW;

    int* ws_idx = (int*)d_ws;                       // 512*512 ints = 1 MB
    int* ws_cnt = ws_idx + (size_t)BB * MM * SS;    // 512 ints

    k1_select<<<BB * MM, 512, 0, stream>>>(points, boxes, ws_idx, ws_cnt, out_flag);
    k2_gather<<<BB * MM * BLOCKS_PER_BOX, 256, 0, stream>>>(points, feats,
                                                            ws_idx, ws_cnt, out_feat);
}

// Round 6
// 70.066 us; speedup vs baseline: 1.3776x; 1.3776x over previous
//
#include <hip/hip_runtime.h>
#include <math.h>

#define BB 4
#define NN 16384
#define CC 128
#define MM 128
#define SS 512
#define OUT_ROW 131                    // 3 coords + 128 features
#define NSEG 256                       // 16384 / 64 segments per box
#define ELEMS_PER_BOX (SS * OUT_ROW)   // 67072 (multiple of 1024)
#define NQUAD (BB * MM * ELEMS_PER_BOX / 4)  // 8,585,216 float4s

typedef float f32x4 __attribute__((ext_vector_type(4)));

// ---------------- K1: per-box stable in-box index selection ----------------
// 512 blocks (one per box) x 512 threads (8 waves).
// Emits ws_idx[bm][0..SS) with the row%cnt wrap ALREADY applied.
__global__ __launch_bounds__(512) void k1_select(
    const float* __restrict__ points,   // (B, N, 3)
    const float* __restrict__ boxes,    // (B, M, 7)
    int* __restrict__ ws_idx,           // (B*M, SS)
    int* __restrict__ ws_cnt,           // (B*M)
    float* __restrict__ out_flag)       // (B*M) as float 0/1
{
    const int bm   = blockIdx.x;
    const int b    = bm >> 7;
    const int m    = bm & (MM - 1);
    const int tid  = threadIdx.x;
    const int lane = tid & 63;
    const int wave = tid >> 6;

    __shared__ unsigned long long s_mask[NSEG];
    __shared__ int s_wsum[4];

    // box params, enlarged: cz -= 0.5, d* += 1.0
    const float* bx = boxes + (size_t)(b * MM + m) * 7;
    const float cx  = bx[0];
    const float cy  = bx[1];
    const float cz  = __fadd_rn(bx[2], -0.5f);
    const float hx  = __fmul_rn(__fadd_rn(bx[3], 1.0f), 0.5f);
    const float hy  = __fmul_rn(__fadd_rn(bx[4], 1.0f), 0.5f);
    const float hz  = __fmul_rn(__fadd_rn(bx[5], 1.0f), 0.5f);
    const float yaw = bx[6];
    const float cosa = (float)cos((double)yaw);
    const float sina = (float)sin((double)yaw);
    const float zc   = __fadd_rn(cz, hz);

    const float* pbase = points + (size_t)b * NN * 3;

    // ---- Pass A: wave w handles segments [w*32, w*32+32) ----
    #pragma unroll 4
    for (int k = 0; k < 32; ++k) {
        const int s = wave * 32 + k;
        const int i = s * 64 + lane;
        const float px = pbase[i * 3 + 0];
        const float py = pbase[i * 3 + 1];
        const float pz = pbase[i * 3 + 2];
        const float sx = __fadd_rn(px, -cx);
        const float sy = __fadd_rn(py, -cy);
        const float lx = __fadd_rn(__fmul_rn(sx, cosa), __fmul_rn(sy, sina));
        const float ly = __fadd_rn(__fmul_rn(-sx, sina), __fmul_rn(sy, cosa));
        const bool in_box = (fabsf(lx) < hx) & (fabsf(ly) < hy) &
                            (fabsf(__fadd_rn(pz, -zc)) <= hz);
        const unsigned long long mask = __ballot(in_box);
        if (lane == 0) s_mask[s] = mask;
    }
    __syncthreads();

    // ---- Pass B: prefix scan over 256 segment counts (threads 0..255) ----
    unsigned long long mymask = 0ull;
    int c = 0;
    if (tid < NSEG) {
        mymask = s_mask[tid];
        c = __popcll(mymask);
    }
    int inc = c;
    #pragma unroll
    for (int d = 1; d < 64; d <<= 1) {
        int v = __shfl_up(inc, d);
        if (lane >= d) inc += v;
    }
    if (tid < NSEG && lane == 63) s_wsum[wave] = inc;
    __syncthreads();

    int woff = 0, total = 0;
    #pragma unroll
    for (int w = 0; w < 4; ++w) {
        const int v = s_wsum[w];
        if (w < wave) woff += v;
        total += v;
    }

    int* dst = ws_idx + (size_t)bm * SS;

    // ---- Pass C: emit indices (stable ascending order), first SS only ----
    if (tid < NSEG) {
        int base = woff + inc - c;          // exclusive prefix
        if (base < SS) {
            unsigned long long mk = mymask;
            while (mk) {
                const int bit = __ffsll(mk) - 1;
                mk &= mk - 1;
                dst[base] = tid * 64 + bit;
                if (++base >= SS) break;
            }
        }
    }
    __syncthreads();

    // ---- Pass D: expand with row % cnt wrap so K2 needs no division ----
    const int cnt = total;
    if (cnt > 0) {
        for (int row = cnt + tid; row < SS; row += 512)
            dst[row] = dst[row % cnt];
    }
    if (tid == 0) {
        ws_cnt[bm] = cnt;
        out_flag[bm] = (cnt == 0) ? 1.0f : 0.0f;
    }
}

// ---------------- K2: persistent grid-stride float4 streaming gather ----------------
// 2048 blocks x 256 threads = full residency (8 blocks/CU), ~16 float4 per
// thread. One dwordx4 NT store per iteration (1 KB per wave-instruction).
// Quads never cross a box (ELEMS_PER_BOX % 1024 == 0); bm is wave-uniform.
__global__ __launch_bounds__(256) void k2_gather(
    const float* __restrict__ points,
    const float* __restrict__ feats,    // (B, N, C)
    const int* __restrict__ ws_idx,
    const int* __restrict__ ws_cnt,
    float* __restrict__ out_feat)       // (B, M, S, 131)
{
    const int stride = gridDim.x * blockDim.x;
    for (int q = blockIdx.x * blockDim.x + threadIdx.x; q < NQUAD; q += stride) {
        const int e   = q * 4;
        const int bm  = e / ELEMS_PER_BOX;
        const int rem = e - bm * ELEMS_PER_BOX;
        const int cnt = ws_cnt[bm];

        f32x4 v = (f32x4)0.0f;
        if (cnt > 0) {
            const int b = bm >> 7;
            const float* pb = points + (size_t)b * NN * 3;
            const float* fb = feats + (size_t)b * NN * CC;
            const int* idx = ws_idx + (size_t)bm * SS;

            int row = rem / OUT_ROW;
            int col = rem - row * OUT_ROW;
            #pragma unroll
            for (int j = 0; j < 4; ++j) {
                const int pi = idx[row];
                v[j] = (col < 3) ? pb[pi * 3 + col] : fb[(size_t)pi * CC + (col - 3)];
                if (++col == OUT_ROW) { col = 0; ++row; }
            }
        }
        __builtin_nontemporal_store(v, (f32x4*)out_feat + q);
    }
}

extern "C" void kernel_launch(void* const* d_in, const int* in_sizes, int n_in,
                              void* d_out, int out_size, void* d_ws, size_t ws_size,
                              hipStream_t stream) {
    const float* points = (const float*)d_in[0];
    const float* feats  = (const float*)d_in[1];
    const float* boxes  = (const float*)d_in[2];
    float* out_feat = (float*)d_out;
    float* out_flag = (float*)d_out + (size_t)BB * MM * SS * OUT_ROW;

    int* ws_idx = (int*)d_ws;                       // 512*512 ints = 1 MB
    int* ws_cnt = ws_idx + (size_t)BB * MM * SS;    // 512 ints

    k1_select<<<BB * MM, 512, 0, stream>>>(points, boxes, ws_idx, ws_cnt, out_flag);
    k2_gather<<<2048, 256, 0, stream>>>(points, feats, ws_idx, ws_cnt, out_feat);
}

// Round 7
// 56.107 us; speedup vs baseline: 1.7203x; 1.2488x over previous
//
#include <hip/hip_runtime.h>
#include <math.h>

#define BB 4
#define NN 16384
#define CC 128
#define MM 128
#define SS 512
#define OUT_ROW 131                    // 3 coords + 128 features
#define NSEG 256                       // 16384 / 64 segments per box
#define ELEMS_PER_BOX (SS * OUT_ROW)   // 67072
#define G 8                            // row-groups per box
#define RPG (SS / G)                   // 64 rows per group
#define TILE_F4 (RPG * OUT_ROW / 4)    // 2096 float4s per block tile

typedef float f32x4 __attribute__((ext_vector_type(4)));

// ---------------- K1: per-box stable in-box index selection ----------------
// 512 blocks (one per box) x 512 threads (8 waves).
// Emits ws_idx[bm][0..SS) with the row%cnt wrap ALREADY applied.
__global__ __launch_bounds__(512) void k1_select(
    const float* __restrict__ points,   // (B, N, 3)
    const float* __restrict__ boxes,    // (B, M, 7)
    int* __restrict__ ws_idx,           // (B*M, SS)
    int* __restrict__ ws_cnt,           // (B*M)
    float* __restrict__ out_flag)       // (B*M) as float 0/1
{
    const int bm   = blockIdx.x;
    const int b    = bm >> 7;
    const int m    = bm & (MM - 1);
    const int tid  = threadIdx.x;
    const int lane = tid & 63;
    const int wave = tid >> 6;

    __shared__ unsigned long long s_mask[NSEG];
    __shared__ int s_wsum[4];

    // box params, enlarged: cz -= 0.5, d* += 1.0
    const float* bx = boxes + (size_t)(b * MM + m) * 7;
    const float cx  = bx[0];
    const float cy  = bx[1];
    const float cz  = __fadd_rn(bx[2], -0.5f);
    const float hx  = __fmul_rn(__fadd_rn(bx[3], 1.0f), 0.5f);
    const float hy  = __fmul_rn(__fadd_rn(bx[4], 1.0f), 0.5f);
    const float hz  = __fmul_rn(__fadd_rn(bx[5], 1.0f), 0.5f);
    const float yaw = bx[6];
    const float cosa = (float)cos((double)yaw);
    const float sina = (float)sin((double)yaw);
    const float zc   = __fadd_rn(cz, hz);

    const float* pbase = points + (size_t)b * NN * 3;

    // ---- Pass A: wave w handles segments [w*32, w*32+32) ----
    #pragma unroll 4
    for (int k = 0; k < 32; ++k) {
        const int s = wave * 32 + k;
        const int i = s * 64 + lane;
        const float px = pbase[i * 3 + 0];
        const float py = pbase[i * 3 + 1];
        const float pz = pbase[i * 3 + 2];
        const float sx = __fadd_rn(px, -cx);
        const float sy = __fadd_rn(py, -cy);
        const float lx = __fadd_rn(__fmul_rn(sx, cosa), __fmul_rn(sy, sina));
        const float ly = __fadd_rn(__fmul_rn(-sx, sina), __fmul_rn(sy, cosa));
        const bool in_box = (fabsf(lx) < hx) & (fabsf(ly) < hy) &
                            (fabsf(__fadd_rn(pz, -zc)) <= hz);
        const unsigned long long mask = __ballot(in_box);
        if (lane == 0) s_mask[s] = mask;
    }
    __syncthreads();

    // ---- Pass B: prefix scan over 256 segment counts (threads 0..255) ----
    unsigned long long mymask = 0ull;
    int c = 0;
    if (tid < NSEG) {
        mymask = s_mask[tid];
        c = __popcll(mymask);
    }
    int inc = c;
    #pragma unroll
    for (int d = 1; d < 64; d <<= 1) {
        int v = __shfl_up(inc, d);
        if (lane >= d) inc += v;
    }
    if (tid < NSEG && lane == 63) s_wsum[wave] = inc;
    __syncthreads();

    int woff = 0, total = 0;
    #pragma unroll
    for (int w = 0; w < 4; ++w) {
        const int v = s_wsum[w];
        if (w < wave) woff += v;
        total += v;
    }

    int* dst = ws_idx + (size_t)bm * SS;

    // ---- Pass C: emit indices (stable ascending order), first SS only ----
    if (tid < NSEG) {
        int base = woff + inc - c;          // exclusive prefix
        if (base < SS) {
            unsigned long long mk = mymask;
            while (mk) {
                const int bit = __ffsll(mk) - 1;
                mk &= mk - 1;
                dst[base] = tid * 64 + bit;
                if (++base >= SS) break;
            }
        }
    }
    __syncthreads();

    // ---- Pass D: expand with row % cnt wrap so K2 needs no division ----
    const int cnt = total;
    if (cnt > 0) {
        for (int row = cnt + tid; row < SS; row += 512)
            dst[row] = dst[row % cnt];
    }
    if (tid == 0) {
        ws_cnt[bm] = cnt;
        out_flag[bm] = (cnt == 0) ? 1.0f : 0.0f;
    }
}

// ---------------- K2: LDS-bounce gather ----------------
// 4096 blocks (box x 8 row-groups) x 256 threads (4 waves).
// Phase A: independent float4 gathers (idx staged in LDS) -> LDS tile [64][131].
// Phase B: stream the contiguous 33,536 B tile out as aligned NT dwordx4.
__global__ __launch_bounds__(256) void k2_gather(
    const float* __restrict__ points,
    const float* __restrict__ feats,    // (B, N, C)
    const int* __restrict__ ws_idx,
    const int* __restrict__ ws_cnt,
    float* __restrict__ out_feat)       // (B, M, S, 131)
{
    const int blk  = blockIdx.x;
    const int bm   = blk >> 3;
    const int g    = blk & (G - 1);
    const int row0 = g * RPG;
    const int tid  = threadIdx.x;

    const int cnt = ws_cnt[bm];
    float* oreg = out_feat + (size_t)bm * ELEMS_PER_BOX + (size_t)row0 * OUT_ROW;

    if (cnt == 0) {
        const f32x4 z = (f32x4)0.0f;
        for (int e4 = tid; e4 < TILE_F4; e4 += 256)
            __builtin_nontemporal_store(z, (f32x4*)oreg + e4);
        return;
    }

    __shared__ int   s_pi[RPG];
    __shared__ float s_tile[RPG * OUT_ROW];   // 33,536 B

    if (tid < RPG)
        s_pi[tid] = ws_idx[(size_t)bm * SS + row0 + tid];  // wrap pre-applied in K1
    __syncthreads();

    const int b = bm >> 7;
    const float* pb = points + (size_t)b * NN * 3;
    const float* fb = feats + (size_t)b * NN * CC;
    const int lane = tid & 63;
    const int wave = tid >> 6;
    const int half = lane >> 5;
    const int sl   = lane & 31;

    // coords: 192 threads cover 64 rows x 3
    if (tid < RPG * 3) {
        const int row = tid / 3, c = tid - row * 3;
        s_tile[row * OUT_ROW + c] = pb[s_pi[row] * 3 + c];
    }

    // features: 8 unrolled passes, 8 independent float4 gathers in flight/lane
    #pragma unroll
    for (int p = 0; p < 8; ++p) {
        const int row = p * 8 + wave * 2 + half;
        const int pi  = s_pi[row];
        const f32x4 v = *(const f32x4*)(fb + (size_t)pi * CC + sl * 4);
        float* d = &s_tile[row * OUT_ROW + 3 + sl * 4];
        d[0] = v.x; d[1] = v.y; d[2] = v.z; d[3] = v.w;
    }
    __syncthreads();

    // stream out: 2096 aligned NT dwordx4
    #pragma unroll 4
    for (int e4 = tid; e4 < TILE_F4; e4 += 256) {
        const int e = e4 * 4;
        f32x4 v;
        v.x = s_tile[e + 0]; v.y = s_tile[e + 1];
        v.z = s_tile[e + 2]; v.w = s_tile[e + 3];
        __builtin_nontemporal_store(v, (f32x4*)oreg + e4);
    }
}

extern "C" void kernel_launch(void* const* d_in, const int* in_sizes, int n_in,
                              void* d_out, int out_size, void* d_ws, size_t ws_size,
                              hipStream_t stream) {
    const float* points = (const float*)d_in[0];
    const float* feats  = (const float*)d_in[1];
    const float* boxes  = (const float*)d_in[2];
    float* out_feat = (float*)d_out;
    float* out_flag = (float*)d_out + (size_t)BB * MM * SS * OUT_ROW;

    int* ws_idx = (int*)d_ws;                       // 512*512 ints = 1 MB
    int* ws_cnt = ws_idx + (size_t)BB * MM * SS;    // 512 ints

    k1_select<<<BB * MM, 512, 0, stream>>>(points, boxes, ws_idx, ws_cnt, out_flag);
    k2_gather<<<BB * MM * G, 256, 0, stream>>>(points, feats, ws_idx, ws_cnt, out_feat);
}

// Round 8
// 48.616 us; speedup vs baseline: 1.9854x; 1.1541x over previous
//
#include <hip/hip_runtime.h>
#include <math.h>

#define BB 4
#define NN 16384
#define CC 128
#define MM 128
#define SS 512
#define OUT_ROW 131                    // 3 coords + 128 features
#define NSEG 256                       // 16384 / 64 segments per box
#define ELEMS_PER_BOX (SS * OUT_ROW)   // 67072
#define G2 16                          // row-groups per box (32 rows each)
#define RPG2 32
#define TILE2_F4 (RPG2 * OUT_ROW / 4)  // 1048 float4s per tile

typedef float f32x4 __attribute__((ext_vector_type(4)));

// ---------------- K1: per-box stable in-box index selection ----------------
// 512 blocks (one per box) x 512 threads (8 waves).
// Emits ws_idx[bm][0..SS) with the row%cnt wrap ALREADY applied.
__global__ __launch_bounds__(512) void k1_select(
    const float* __restrict__ points,   // (B, N, 3)
    const float* __restrict__ boxes,    // (B, M, 7)
    int* __restrict__ ws_idx,           // (B*M, SS)
    int* __restrict__ ws_cnt,           // (B*M)
    float* __restrict__ out_flag)       // (B*M) as float 0/1
{
    const int bm   = blockIdx.x;
    const int b    = bm >> 7;
    const int m    = bm & (MM - 1);
    const int tid  = threadIdx.x;
    const int lane = tid & 63;
    const int wave = tid >> 6;

    __shared__ unsigned long long s_mask[NSEG];
    __shared__ int s_wsum[4];

    // box params, enlarged: cz -= 0.5, d* += 1.0
    const float* bx = boxes + (size_t)(b * MM + m) * 7;
    const float cx  = bx[0];
    const float cy  = bx[1];
    const float cz  = __fadd_rn(bx[2], -0.5f);
    const float hx  = __fmul_rn(__fadd_rn(bx[3], 1.0f), 0.5f);
    const float hy  = __fmul_rn(__fadd_rn(bx[4], 1.0f), 0.5f);
    const float hz  = __fmul_rn(__fadd_rn(bx[5], 1.0f), 0.5f);
    const float yaw = bx[6];
    const float cosa = (float)cos((double)yaw);
    const float sina = (float)sin((double)yaw);
    const float zc   = __fadd_rn(cz, hz);

    const float* pbase = points + (size_t)b * NN * 3;

    // ---- Pass A: wave w handles segments [w*32, w*32+32) ----
    #pragma unroll 4
    for (int k = 0; k < 32; ++k) {
        const int s = wave * 32 + k;
        const int i = s * 64 + lane;
        const float px = pbase[i * 3 + 0];
        const float py = pbase[i * 3 + 1];
        const float pz = pbase[i * 3 + 2];
        const float sx = __fadd_rn(px, -cx);
        const float sy = __fadd_rn(py, -cy);
        const float lx = __fadd_rn(__fmul_rn(sx, cosa), __fmul_rn(sy, sina));
        const float ly = __fadd_rn(__fmul_rn(-sx, sina), __fmul_rn(sy, cosa));
        const bool in_box = (fabsf(lx) < hx) & (fabsf(ly) < hy) &
                            (fabsf(__fadd_rn(pz, -zc)) <= hz);
        const unsigned long long mask = __ballot(in_box);
        if (lane == 0) s_mask[s] = mask;
    }
    __syncthreads();

    // ---- Pass B: prefix scan over 256 segment counts (threads 0..255) ----
    unsigned long long mymask = 0ull;
    int c = 0;
    if (tid < NSEG) {
        mymask = s_mask[tid];
        c = __popcll(mymask);
    }
    int inc = c;
    #pragma unroll
    for (int d = 1; d < 64; d <<= 1) {
        int v = __shfl_up(inc, d);
        if (lane >= d) inc += v;
    }
    if (tid < NSEG && lane == 63) s_wsum[wave] = inc;
    __syncthreads();

    int woff = 0, total = 0;
    #pragma unroll
    for (int w = 0; w < 4; ++w) {
        const int v = s_wsum[w];
        if (w < wave) woff += v;
        total += v;
    }

    int* dst = ws_idx + (size_t)bm * SS;

    // ---- Pass C: emit indices (stable ascending order), first SS only ----
    if (tid < NSEG) {
        int base = woff + inc - c;          // exclusive prefix
        if (base < SS) {
            unsigned long long mk = mymask;
            while (mk) {
                const int bit = __ffsll(mk) - 1;
                mk &= mk - 1;
                dst[base] = tid * 64 + bit;
                if (++base >= SS) break;
            }
        }
    }
    __syncthreads();

    // ---- Pass D: expand with row % cnt wrap so K2 needs no division ----
    const int cnt = total;
    if (cnt > 0) {
        for (int row = cnt + tid; row < SS; row += 512)
            dst[row] = dst[row % cnt];
    }
    if (tid == 0) {
        ws_cnt[bm] = cnt;
        out_flag[bm] = (cnt == 0) ? 1.0f : 0.0f;
    }
}

// ---------------- K2: LDS-bounce gather, 32-row tiles ----------------
// 8192 blocks x 256 threads (4 waves). LDS 16.75 KB -> 8 blocks/CU = 100% occ.
// Row indices live in registers (shfl); single barrier per block.
// Bijective XCD swizzle: each XCD gets 64 consecutive boxes (8 MB working set).
__global__ __launch_bounds__(256) void k2_gather(
    const float* __restrict__ points,
    const float* __restrict__ feats,    // (B, N, C)
    const int* __restrict__ ws_idx,
    const int* __restrict__ ws_cnt,
    float* __restrict__ out_feat)       // (B, M, S, 131)
{
    const int orig = blockIdx.x;
    const int blk  = ((orig & 7) << 10) | (orig >> 3);   // 8192 = 8 XCD x 1024
    const int bm   = blk >> 4;
    const int g    = blk & (G2 - 1);
    const int row0 = g << 5;
    const int tid  = threadIdx.x;

    const int cnt = ws_cnt[bm];
    float* oreg = out_feat + (size_t)bm * ELEMS_PER_BOX + (size_t)row0 * OUT_ROW;

    if (cnt == 0) {
        const f32x4 z = (f32x4)0.0f;
        for (int e4 = tid; e4 < TILE2_F4; e4 += 256)
            __builtin_nontemporal_store(z, (f32x4*)oreg + e4);
        return;
    }

    __shared__ float s_tile[RPG2 * OUT_ROW];   // 16,768 B

    const int b = bm >> 7;
    const float* pb = points + (size_t)b * NN * 3;
    const float* fb = feats + (size_t)b * NN * CC;
    const int lane = tid & 63;
    const int wave = tid >> 6;
    const int half = lane >> 5;
    const int sl   = lane & 31;
    const int* idx = ws_idx + (size_t)bm * SS + row0;

    // lane r (mod 32) holds idx[r]; gathers fetch via shfl — no LDS, no barrier
    const int idxreg = idx[lane & 31];

    // coords: 96 threads cover 32 rows x 3 (direct L2-hit idx reads)
    if (tid < RPG2 * 3) {
        const int row = tid / 3, c = tid - row * 3;
        s_tile[row * OUT_ROW + c] = pb[idx[row] * 3 + c];
    }

    // features: 4 passes, independent float4 gathers
    #pragma unroll
    for (int p = 0; p < 4; ++p) {
        const int row = p * 8 + wave * 2 + half;
        const int pi  = __shfl(idxreg, row);
        const f32x4 v = *(const f32x4*)(fb + (size_t)pi * CC + sl * 4);
        float* d = &s_tile[row * OUT_ROW + 3 + sl * 4];
        d[0] = v.x; d[1] = v.y; d[2] = v.z; d[3] = v.w;
    }
    __syncthreads();

    // stream out: 1048 aligned NT dwordx4
    for (int e4 = tid; e4 < TILE2_F4; e4 += 256) {
        const int e = e4 * 4;
        f32x4 v;
        v.x = s_tile[e + 0]; v.y = s_tile[e + 1];
        v.z = s_tile[e + 2]; v.w = s_tile[e + 3];
        __builtin_nontemporal_store(v, (f32x4*)oreg + e4);
    }
}

extern "C" void kernel_launch(void* const* d_in, const int* in_sizes, int n_in,
                              void* d_out, int out_size, void* d_ws, size_t ws_size,
                              hipStream_t stream) {
    const float* points = (const float*)d_in[0];
    const float* feats  = (const float*)d_in[1];
    const float* boxes  = (const float*)d_in[2];
    float* out_feat = (float*)d_out;
    float* out_flag = (float*)d_out + (size_t)BB * MM * SS * OUT_ROW;

    int* ws_idx = (int*)d_ws;                       // 512*512 ints = 1 MB
    int* ws_cnt = ws_idx + (size_t)BB * MM * SS;    // 512 ints

    k1_select<<<BB * MM, 512, 0, stream>>>(points, boxes, ws_idx, ws_cnt, out_flag);
    k2_gather<<<BB * MM * G2, 256, 0, stream>>>(points, feats, ws_idx, ws_cnt, out_feat);
}